// Round 1
// baseline (428.388 us; speedup 1.0000x reference)
//
#include <hip/hip_runtime.h>
#include <math.h>

#define CC    192
#define TC3   576
#define HW    16384
#define NB    4
#define SPLIT 16
#define EPSN  1e-12f

__device__ __forceinline__ float wsum(float v){
#pragma unroll
  for (int off = 32; off > 0; off >>= 1) v += __shfl_xor(v, off, 64);
  return v;
}
__device__ __forceinline__ float wmax(float v){
#pragma unroll
  for (int off = 32; off > 0; off >>= 1) v = fmaxf(v, __shfl_xor(v, off, 64));
  return v;
}

// C[m][n] = sum_k A[k][m] * B[k][n]   (A: [K][M] row-major, B: [K][N] row-major)
// 64x64 tile, BK=16, 256 threads, 4x4 per thread. Requires M,N %64==0, K%16==0.
__global__ __launch_bounds__(256) void gemm_ktkn(
    const float* __restrict__ A, long sA,
    const float* __restrict__ Bm, long sB,
    float* __restrict__ Cm, long sC,
    int M, int N, int K)
{
  const float* Ab = A  + (long)blockIdx.z * sA;
  const float* Bb = Bm + (long)blockIdx.z * sB;
  float*       Cb = Cm + (long)blockIdx.z * sC;
  int m0 = blockIdx.y * 64, n0 = blockIdx.x * 64;
  __shared__ float As[16][64];
  __shared__ float Bs[16][64];
  int t  = threadIdx.x;
  int ty = t >> 4, tx = t & 15;
  int lk = t >> 4, lm = (t & 15) << 2;
  float acc[4][4] = {};
  for (int k0 = 0; k0 < K; k0 += 16) {
    *reinterpret_cast<float4*>(&As[lk][lm]) =
        *reinterpret_cast<const float4*>(&Ab[(long)(k0 + lk) * M + m0 + lm]);
    *reinterpret_cast<float4*>(&Bs[lk][lm]) =
        *reinterpret_cast<const float4*>(&Bb[(long)(k0 + lk) * N + n0 + lm]);
    __syncthreads();
#pragma unroll
    for (int kk = 0; kk < 16; ++kk) {
      float4 a4 = *reinterpret_cast<const float4*>(&As[kk][ty << 2]);
      float4 b4 = *reinterpret_cast<const float4*>(&Bs[kk][tx << 2]);
      float a[4] = {a4.x, a4.y, a4.z, a4.w};
      float b[4] = {b4.x, b4.y, b4.z, b4.w};
#pragma unroll
      for (int i = 0; i < 4; i++)
#pragma unroll
        for (int j = 0; j < 4; j++) acc[i][j] += a[i] * b[j];
    }
    __syncthreads();
  }
#pragma unroll
  for (int i = 0; i < 4; i++) {
    float4 v = make_float4(acc[i][0], acc[i][1], acc[i][2], acc[i][3]);
    *reinterpret_cast<float4*>(&Cb[(long)(m0 + (ty << 2) + i) * N + n0 + (tx << 2)]) = v;
  }
}

// one block per (row j, batch): invn[b*384+j] = 1/max(||T[j,:]||, eps)   (j < 384: q rows then k rows)
__global__ __launch_bounds__(256) void colnorms(
    const float* __restrict__ T, long sT, float* __restrict__ invn)
{
  int j = blockIdx.x;
  int b = blockIdx.y;
  const float4* row = reinterpret_cast<const float4*>(T + (long)b * sT + (long)j * HW);
  float s = 0.f;
  for (int i = threadIdx.x; i < HW / 4; i += 256) {
    float4 v = row[i];
    s += v.x * v.x + v.y * v.y + v.z * v.z + v.w * v.w;
  }
  s = wsum(s);
  __shared__ float red[4];
  if ((threadIdx.x & 63) == 0) red[threadIdx.x >> 6] = s;
  __syncthreads();
  if (threadIdx.x == 0) {
    float tot = red[0] + red[1] + red[2] + red[3];
    invn[b * 384 + j] = 1.f / fmaxf(sqrtf(tot), EPSN);
  }
}

// Gpart[(b*SPLIT+chunk)][c][d] = sum over n-chunk of K[c][n]*Q[d][n]
// K = T rows 192..383, Q = T rows 0..191. 64x64 tile, BK=16, split-K over SPLIT chunks.
__global__ __launch_bounds__(256) void gram_nt(
    const float* __restrict__ T, long sT, float* __restrict__ Gpart)
{
  int b     = blockIdx.z;
  int tile  = blockIdx.x;          // 0..8
  int chunk = blockIdx.y;          // 0..SPLIT-1
  int c0 = (tile / 3) * 64, d0 = (tile % 3) * 64;
  const float* Kp = T + (long)b * sT + (long)CC * HW;
  const float* Qp = T + (long)b * sT;
  __shared__ float Ks[16][65];
  __shared__ float Qs[16][65];
  int t  = threadIdx.x;
  int ty = t >> 4, tx = t & 15;
  int cc = t >> 2, q = (t & 3) << 2;
  float acc[4][4] = {};
  long nbase = (long)chunk * (HW / SPLIT);
  for (int k0 = 0; k0 < HW / SPLIT; k0 += 16) {
    float4 ka = *reinterpret_cast<const float4*>(&Kp[(long)(c0 + cc) * HW + nbase + k0 + q]);
    float4 qa = *reinterpret_cast<const float4*>(&Qp[(long)(d0 + cc) * HW + nbase + k0 + q]);
    Ks[q + 0][cc] = ka.x; Ks[q + 1][cc] = ka.y; Ks[q + 2][cc] = ka.z; Ks[q + 3][cc] = ka.w;
    Qs[q + 0][cc] = qa.x; Qs[q + 1][cc] = qa.y; Qs[q + 2][cc] = qa.z; Qs[q + 3][cc] = qa.w;
    __syncthreads();
#pragma unroll
    for (int kk = 0; kk < 16; ++kk) {
      float a[4], bb[4];
#pragma unroll
      for (int i = 0; i < 4; i++) a[i]  = Ks[kk][(ty << 2) + i];
#pragma unroll
      for (int j = 0; j < 4; j++) bb[j] = Qs[kk][(tx << 2) + j];
#pragma unroll
      for (int i = 0; i < 4; i++)
#pragma unroll
        for (int j = 0; j < 4; j++) acc[i][j] += a[i] * bb[j];
    }
    __syncthreads();
  }
  float* Gp = Gpart + ((long)b * SPLIT + chunk) * CC * CC;
#pragma unroll
  for (int i = 0; i < 4; i++) {
    float4 v = make_float4(acc[i][0], acc[i][1], acc[i][2], acc[i][3]);
    *reinterpret_cast<float4*>(&Gp[(long)(c0 + (ty << 2) + i) * CC + d0 + (tx << 2)]) = v;
  }
}

// per (b, row c): reduce Gpart over chunks, scale by invnk[c]*invnq[d]*sigma, softmax over d -> S
__global__ __launch_bounds__(64) void softmax_row(
    const float* __restrict__ Gpart, const float* __restrict__ invn,
    const float* __restrict__ sigma, float* __restrict__ S)
{
  int c = blockIdx.x;
  int b = blockIdx.y;
  float sig = sigma[0];
  float ink = invn[b * 384 + 192 + c];
  float l[3];
#pragma unroll
  for (int r = 0; r < 3; ++r) {
    int d = threadIdx.x + 64 * r;
    float s = 0.f;
    for (int ch = 0; ch < SPLIT; ++ch)
      s += Gpart[(((long)b * SPLIT + ch) * CC + c) * CC + d];
    l[r] = s * ink * invn[b * 384 + d] * sig;
  }
  float m = fmaxf(l[0], fmaxf(l[1], l[2]));
  m = wmax(m);
  float e[3], tot = 0.f;
#pragma unroll
  for (int r = 0; r < 3; ++r) { e[r] = __expf(l[r] - m); tot += e[r]; }
  tot = wsum(tot);
  float inv = 1.f / tot;
#pragma unroll
  for (int r = 0; r < 3; ++r) {
    int d = threadIdx.x + 64 * r;
    S[((long)b * CC + c) * CC + d] = e[r] * inv;
  }
}

// C[m][n] = sum_k A[m][k]*B[k][n]  (A row-major [M][K], B row-major [K][N]) — for M = S @ W_lin
__global__ __launch_bounds__(256) void gemm_nn(
    const float* __restrict__ A, long sA,
    const float* __restrict__ Bm, long sB,
    float* __restrict__ Cm, long sC,
    int M, int N, int K)
{
  const float* Ab = A  + (long)blockIdx.z * sA;
  const float* Bb = Bm + (long)blockIdx.z * sB;
  float*       Cb = Cm + (long)blockIdx.z * sC;
  int m0 = blockIdx.y * 64, n0 = blockIdx.x * 64;
  __shared__ float As[16][65];
  __shared__ float Bs[16][64];
  int t  = threadIdx.x;
  int ty = t >> 4, tx = t & 15;
  int mm = t >> 2, q = (t & 3) << 2;
  int lk = t >> 4, ln = (t & 15) << 2;
  float acc[4][4] = {};
  for (int k0 = 0; k0 < K; k0 += 16) {
    float4 av = *reinterpret_cast<const float4*>(&Ab[(long)(m0 + mm) * K + k0 + q]);
    As[q + 0][mm] = av.x; As[q + 1][mm] = av.y; As[q + 2][mm] = av.z; As[q + 3][mm] = av.w;
    *reinterpret_cast<float4*>(&Bs[lk][ln]) =
        *reinterpret_cast<const float4*>(&Bb[(long)(k0 + lk) * N + n0 + ln]);
    __syncthreads();
#pragma unroll
    for (int kk = 0; kk < 16; ++kk) {
      float a[4], bb[4];
#pragma unroll
      for (int i = 0; i < 4; i++) a[i]  = As[kk][(ty << 2) + i];
#pragma unroll
      for (int j = 0; j < 4; j++) bb[j] = Bs[kk][(tx << 2) + j];
#pragma unroll
      for (int i = 0; i < 4; i++)
#pragma unroll
        for (int j = 0; j < 4; j++) acc[i][j] += a[i] * bb[j];
    }
    __syncthreads();
  }
#pragma unroll
  for (int i = 0; i < 4; i++) {
    float4 v = make_float4(acc[i][0], acc[i][1], acc[i][2], acc[i][3]);
    *reinterpret_cast<float4*>(&Cb[(long)(m0 + (ty << 2) + i) * N + n0 + (tx << 2)]) = v;
  }
}

extern "C" void kernel_launch(void* const* d_in, const int* in_sizes, int n_in,
                              void* d_out, int out_size, void* d_ws, size_t ws_size,
                              hipStream_t stream) {
  const float* x     = (const float*)d_in[0];   // [4][192][16384]
  const float* Wqkv  = (const float*)d_in[1];   // [192][576]
  const float* Wlin  = (const float*)d_in[2];   // [192][192]
  const float* sigma = (const float*)d_in[3];   // [1]
  float* out = (float*)d_out;                   // [4][192][16384]
  float* ws  = (float*)d_ws;

  auto floats_for = [](int per) -> size_t {
    return (size_t)per * TC3 * HW        // T (qkv transposed)
         + (size_t)per * 384             // invn
         + (size_t)per * SPLIT * CC * CC // Gram partials
         + (size_t)per * CC * CC         // S
         + (size_t)per * CC * CC;        // M
  };
  int per = (ws_size >= floats_for(NB) * sizeof(float)) ? NB : 1;

  for (int b0 = 0; b0 < NB; b0 += per) {
    float* Tb    = ws;
    float* invn  = Tb    + (size_t)per * TC3 * HW;
    float* Gpart = invn  + (size_t)per * 384;
    float* Sb    = Gpart + (size_t)per * SPLIT * CC * CC;
    float* Mb    = Sb    + (size_t)per * CC * CC;
    const float* xb = x + (size_t)b0 * CC * HW;
    float* ob       = out + (size_t)b0 * CC * HW;

    // 1) T[b][j][n] = sum_c Wqkv[c][j] * x[b][c][n]   (j: [q|k|v] x 192)
    gemm_ktkn<<<dim3(HW / 64, TC3 / 64, per), 256, 0, stream>>>(
        Wqkv, 0L, xb, (long)CC * HW, Tb, (long)TC3 * HW, TC3, HW, CC);
    // 2) inverse token-axis norms for q,k rows
    colnorms<<<dim3(384, per), 256, 0, stream>>>(Tb, (long)TC3 * HW, invn);
    // 3) split-K Gram partials: K_raw^T Q_raw
    gram_nt<<<dim3(9, SPLIT, per), 256, 0, stream>>>(Tb, (long)TC3 * HW, Gpart);
    // 4) reduce + scale + softmax -> S
    softmax_row<<<dim3(CC, per), 64, 0, stream>>>(Gpart, invn, sigma, Sb);
    // 5) M = S @ W_lin  (192x192x192)
    gemm_nn<<<dim3(3, 3, per), 256, 0, stream>>>(
        Sb, (long)CC * CC, Wlin, 0L, Mb, (long)CC * CC, CC, CC, CC);
    // 6) out[b][e][n] = sum_c M[c][e] * V[c][n]   (V = T rows 384..575) -> final layout directly
    gemm_ktkn<<<dim3(HW / 64, CC / 64, per), 256, 0, stream>>>(
        Mb, (long)CC * CC, Tb + (size_t)2 * CC * HW, (long)TC3 * HW,
        ob, (long)CC * HW, CC, HW, CC);
  }
}

// Round 3
// 165.750 us; speedup vs baseline: 2.5845x; 2.5845x over previous
//
#include <hip/hip_runtime.h>

#define CCH 192
#define HWN 16384
#define NB  4
#define SPLIT 16

typedef __attribute__((ext_vector_type(8))) short bf16x8;
typedef __attribute__((ext_vector_type(4))) float f32x4;

__device__ __forceinline__ ushort f2bf(float f) {
  union { float f; unsigned u; } v; v.f = f;
  return (ushort)((v.u + 0x7fffu + ((v.u >> 16) & 1u)) >> 16);
}

__device__ __forceinline__ float wsum(float v) {
#pragma unroll
  for (int off = 32; off > 0; off >>= 1) v += __shfl_xor(v, off, 64);
  return v;
}
__device__ __forceinline__ float wmax(float v) {
#pragma unroll
  for (int off = 32; off > 0; off >>= 1) v = fmaxf(v, __shfl_xor(v, off, 64));
  return v;
}

// K1: x[c][n] f32 -> xT[n][c] bf16, 64x64 LDS tiles
__global__ __launch_bounds__(256) void k1_xpose(const float* __restrict__ x, ushort* __restrict__ xT) {
  int z = blockIdx.z;
  const float* xb = x + (size_t)z * CCH * HWN;
  ushort* xTb = xT + (size_t)z * HWN * CCH;
  int n0 = blockIdx.x * 64, c0 = blockIdx.y * 64;
  __shared__ float L[64][65];
  int t = threadIdx.x;
#pragma unroll
  for (int p = 0; p < 4; ++p) {
    int idx = t + 256 * p;
    int row = idx >> 4, col = (idx & 15) << 2;
    float4 v = *reinterpret_cast<const float4*>(&xb[(size_t)(c0 + row) * HWN + n0 + col]);
    L[row][col] = v.x; L[row][col + 1] = v.y; L[row][col + 2] = v.z; L[row][col + 3] = v.w;
  }
  __syncthreads();
#pragma unroll
  for (int p = 0; p < 4; ++p) {
    int idx = t + 256 * p;
    int nl = idx >> 4, c4 = (idx & 15) << 2;  // covers all 64x64 elems: 1024 threads*iters x 4 chans
    ushort4 o;
    o.x = f2bf(L[c4 + 0][nl]);
    o.y = f2bf(L[c4 + 1][nl]);
    o.z = f2bf(L[c4 + 2][nl]);
    o.w = f2bf(L[c4 + 3][nl]);
    *reinterpret_cast<ushort4*>(&xTb[(size_t)(n0 + nl) * CCH + c0 + c4]) = o;
  }
}

// K2: qkv GEMM. D[n][j] = sum_c xT[n][c] * Wqkv[c][j].
// j-tiles 0..5 -> Tqk[j][n] bf16 (LDS-transpose epilogue) + norm2 partials; 6..8 -> Vt[n][c] bf16.
__global__ __launch_bounds__(256) void k2_qkv(
    const ushort* __restrict__ xT, const float* __restrict__ Wqkv,
    ushort* __restrict__ Tqk, ushort* __restrict__ Vt, float* __restrict__ norm2p)
{
  int z = blockIdx.z;
  const ushort* xTb = xT + (size_t)z * HWN * CCH;
  ushort* Tb = Tqk + (size_t)z * 384 * HWN;
  ushort* Vb = Vt + (size_t)z * HWN * CCH;
  float* npb = norm2p + (size_t)z * 256 * 384;
  int jt = blockIdx.x, nt = blockIdx.y;
  int n0 = nt * 128, j0 = jt * 64;
  __shared__ __align__(16) ushort SM[26112];  // As[128][104] + Ws[64][200] = 52224 B
  ushort* As = SM;
  ushort* Ws = SM + 13312;
  int t = threadIdx.x, l = t & 63, w = t >> 6;
  int wn = w >> 1, wj = w & 1, lg = l >> 4, lr = l & 15;
  for (int i = t; i < 192 * 64; i += 256) {
    int c = i >> 6, jl = i & 63;
    Ws[jl * 200 + c] = f2bf(Wqkv[(size_t)c * 576 + j0 + jl]);
  }
  f32x4 acc[4][2] = {};
  for (int h = 0; h < 2; ++h) {
    __syncthreads();
    for (int i = t; i < 128 * 12; i += 256) {
      int row = i / 12, slot = i % 12;
      *reinterpret_cast<int4*>(&As[row * 104 + slot * 8]) =
          *reinterpret_cast<const int4*>(&xTb[(size_t)(n0 + row) * CCH + 96 * h + slot * 8]);
    }
    __syncthreads();
#pragma unroll
    for (int k3 = 0; k3 < 3; ++k3) {
      bf16x8 a[4], bb[2];
#pragma unroll
      for (int m = 0; m < 4; ++m)
        a[m] = *reinterpret_cast<const bf16x8*>(&As[(64 * wn + 16 * m + lr) * 104 + k3 * 32 + lg * 8]);
#pragma unroll
      for (int f = 0; f < 2; ++f)
        bb[f] = *reinterpret_cast<const bf16x8*>(&Ws[(32 * wj + 16 * f + lr) * 200 + 96 * h + k3 * 32 + lg * 8]);
#pragma unroll
      for (int m = 0; m < 4; ++m)
#pragma unroll
        for (int f = 0; f < 2; ++f)
          acc[m][f] = __builtin_amdgcn_mfma_f32_16x16x32_bf16(a[m], bb[f], acc[m][f], 0, 0, 0);
    }
  }
  if (jt >= 6) {
    int cb = (jt - 6) * 64 + 32 * wj;
#pragma unroll
    for (int m = 0; m < 4; ++m)
#pragma unroll
      for (int f = 0; f < 2; ++f)
#pragma unroll
        for (int r = 0; r < 4; ++r)
          Vb[(size_t)(n0 + 64 * wn + 16 * m + 4 * lg + r) * CCH + cb + 16 * f + lr] = f2bf(acc[m][f][r]);
  } else {
    __syncthreads();
    float* E = reinterpret_cast<float*>(SM) + w * 2112;  // per-wave [64][33] f32, overlays As/Ws
#pragma unroll
    for (int m = 0; m < 4; ++m)
#pragma unroll
      for (int f = 0; f < 2; ++f)
#pragma unroll
        for (int r = 0; r < 4; ++r)
          E[(16 * m + 4 * lg + r) * 33 + 16 * f + lr] = acc[m][f][r];
    __syncthreads();
    int p = l & 31, hi = l >> 5;
    int jb = j0 + 32 * wj;
    for (int it = 0; it < 16; ++it) {
      int jl = 2 * it + hi;
      float e0 = E[(2 * p) * 33 + jl];
      float e1 = E[(2 * p + 1) * 33 + jl];
      float sq = e0 * e0 + e1 * e1;
#pragma unroll
      for (int off = 16; off > 0; off >>= 1) sq += __shfl_xor(sq, off, 64);
      unsigned pk = (unsigned)f2bf(e0) | ((unsigned)f2bf(e1) << 16);
      *reinterpret_cast<unsigned*>(&Tb[(size_t)(jb + jl) * HWN + n0 + 64 * wn + 2 * p]) = pk;
      if (p == 0) npb[(size_t)(2 * nt + wn) * 384 + jb + jl] = sq;
    }
  }
}

// K3: invn[j] = 1/max(sqrt(sum_nb norm2p[nb][j]), eps)
__global__ __launch_bounds__(256) void k3_invn(const float* __restrict__ norm2p, float* __restrict__ invn) {
  int z = blockIdx.y, j = blockIdx.x;
  const float* npb = norm2p + (size_t)z * 256 * 384;
  int t = threadIdx.x;
  float s = npb[(size_t)t * 384 + j];
  s = wsum(s);
  __shared__ float red[4];
  if ((t & 63) == 0) red[t >> 6] = s;
  __syncthreads();
  if (t == 0) {
    float tot = red[0] + red[1] + red[2] + red[3];
    invn[(size_t)z * 384 + j] = 1.f / fmaxf(sqrtf(tot), 1e-12f);
  }
}

// K4: Gpart[chunk][c][d] = sum over n-chunk of K[c][n]*Q[d][n], bf16 MFMA
__global__ __launch_bounds__(256) void k4_gram(const ushort* __restrict__ Tqk, float* __restrict__ Gpart) {
  int z = blockIdx.z;
  const ushort* Tb = Tqk + (size_t)z * 384 * HWN;
  float* Gb = Gpart + (size_t)z * SPLIT * CCH * CCH;
  int tile = blockIdx.x, chunk = blockIdx.y;
  int ct = tile / 3, dt = tile % 3;
  __shared__ __align__(16) ushort Ks[64 * 72];
  __shared__ __align__(16) ushort Qs[64 * 72];
  int t = threadIdx.x, l = t & 63, w = t >> 6;
  int wc = w >> 1, wd = w & 1, lg = l >> 4, lr = l & 15;
  f32x4 acc[2][2] = {};
  for (int s = 0; s < 16; ++s) {
    int nb = chunk * 1024 + s * 64;
    for (int i = t; i < 512; i += 256) {
      int row = i >> 3, sl = i & 7;
      *reinterpret_cast<int4*>(&Ks[row * 72 + sl * 8]) =
          *reinterpret_cast<const int4*>(&Tb[(size_t)(192 + ct * 64 + row) * HWN + nb + sl * 8]);
      *reinterpret_cast<int4*>(&Qs[row * 72 + sl * 8]) =
          *reinterpret_cast<const int4*>(&Tb[(size_t)(dt * 64 + row) * HWN + nb + sl * 8]);
    }
    __syncthreads();
#pragma unroll
    for (int hh = 0; hh < 2; ++hh) {
      bf16x8 a[2], bb[2];
#pragma unroll
      for (int m = 0; m < 2; ++m)
        a[m] = *reinterpret_cast<const bf16x8*>(&Ks[(32 * wc + 16 * m + lr) * 72 + hh * 32 + lg * 8]);
#pragma unroll
      for (int f = 0; f < 2; ++f)
        bb[f] = *reinterpret_cast<const bf16x8*>(&Qs[(32 * wd + 16 * f + lr) * 72 + hh * 32 + lg * 8]);
#pragma unroll
      for (int m = 0; m < 2; ++m)
#pragma unroll
        for (int f = 0; f < 2; ++f)
          acc[m][f] = __builtin_amdgcn_mfma_f32_16x16x32_bf16(a[m], bb[f], acc[m][f], 0, 0, 0);
    }
    __syncthreads();
  }
#pragma unroll
  for (int m = 0; m < 2; ++m)
#pragma unroll
    for (int f = 0; f < 2; ++f)
#pragma unroll
      for (int r = 0; r < 4; ++r)
        Gb[(size_t)(chunk * CCH + ct * 64 + 32 * wc + 16 * m + 4 * lg + r) * CCH +
           dt * 64 + 32 * wd + 16 * f + lr] = acc[m][f][r];
}

// K5: reduce Gpart over chunks, scale, softmax over d -> S
__global__ __launch_bounds__(64) void k5_softmax(
    const float* __restrict__ Gpart, const float* __restrict__ invn,
    const float* __restrict__ sigma, float* __restrict__ S)
{
  int c = blockIdx.x, z = blockIdx.y;
  const float* Gb = Gpart + (size_t)z * SPLIT * CCH * CCH;
  const float* inb = invn + (size_t)z * 384;
  float sig = sigma[0];
  float ink = inb[192 + c];
  float lv[3];
#pragma unroll
  for (int r = 0; r < 3; ++r) {
    int d = threadIdx.x + 64 * r;
    float s = 0.f;
    for (int ch = 0; ch < SPLIT; ++ch)
      s += Gb[(size_t)(ch * CCH + c) * CCH + d];
    lv[r] = s * ink * inb[d] * sig;
  }
  float m = fmaxf(lv[0], fmaxf(lv[1], lv[2]));
  m = wmax(m);
  float e[3], tot = 0.f;
#pragma unroll
  for (int r = 0; r < 3; ++r) { e[r] = __expf(lv[r] - m); tot += e[r]; }
  tot = wsum(tot);
  float inv = 1.f / tot;
  float* Sb = S + (size_t)z * CCH * CCH;
#pragma unroll
  for (int r = 0; r < 3; ++r) Sb[(size_t)c * CCH + threadIdx.x + 64 * r] = e[r] * inv;
}

// K6: Mt[e][c] = sum_d S[c][d] * Wlin[d][e]  (bf16 out, transposed for K7 A-side)
__global__ __launch_bounds__(192) void k6_mlin(
    const float* __restrict__ S, const float* __restrict__ Wlin, ushort* __restrict__ Mt)
{
  int z = blockIdx.y, c = blockIdx.x, e = threadIdx.x;
  const float* Sb = S + (size_t)z * CCH * CCH;
  float s = 0.f;
  for (int d = 0; d < CCH; ++d) s += Sb[(size_t)c * CCH + d] * Wlin[(size_t)d * CCH + e];
  Mt[(size_t)z * CCH * CCH + (size_t)e * CCH + c] = f2bf(s);
}

// K7: out[e][n] = sum_c Mt[e][c] * Vt[n][c], fp32 stores
__global__ __launch_bounds__(256) void k7_out(
    const ushort* __restrict__ Mt, const ushort* __restrict__ Vt, float* __restrict__ out)
{
  int z = blockIdx.z;
  const ushort* Mb = Mt + (size_t)z * CCH * CCH;
  const ushort* Vb = Vt + (size_t)z * HWN * CCH;
  float* ob = out + (size_t)z * CCH * HWN;
  int et = blockIdx.x, nt = blockIdx.y;
  int e0 = et * 64, n0 = nt * 128;
  __shared__ __align__(16) ushort SM7[26112];  // Vs[128][104] + Ms[64][200]
  ushort* Vs = SM7;
  ushort* Ms = SM7 + 13312;
  int t = threadIdx.x, l = t & 63, w = t >> 6;
  int wn = w >> 1, we = w & 1, lg = l >> 4, lr = l & 15;
  for (int i = t; i < 64 * 24; i += 256) {
    int row = i / 24, slot = i % 24;
    *reinterpret_cast<int4*>(&Ms[row * 200 + slot * 8]) =
        *reinterpret_cast<const int4*>(&Mb[(size_t)(e0 + row) * CCH + slot * 8]);
  }
  f32x4 acc[2][4] = {};
  for (int h = 0; h < 2; ++h) {
    __syncthreads();
    for (int i = t; i < 128 * 12; i += 256) {
      int row = i / 12, slot = i % 12;
      *reinterpret_cast<int4*>(&Vs[row * 104 + slot * 8]) =
          *reinterpret_cast<const int4*>(&Vb[(size_t)(n0 + row) * CCH + 96 * h + slot * 8]);
    }
    __syncthreads();
#pragma unroll
    for (int k3 = 0; k3 < 3; ++k3) {
      bf16x8 a[2], bb[4];
#pragma unroll
      for (int m = 0; m < 2; ++m)
        a[m] = *reinterpret_cast<const bf16x8*>(&Ms[(32 * we + 16 * m + lr) * 200 + 96 * h + k3 * 32 + lg * 8]);
#pragma unroll
      for (int f = 0; f < 4; ++f)
        bb[f] = *reinterpret_cast<const bf16x8*>(&Vs[(64 * wn + 16 * f + lr) * 104 + k3 * 32 + lg * 8]);
#pragma unroll
      for (int m = 0; m < 2; ++m)
#pragma unroll
        for (int f = 0; f < 4; ++f)
          acc[m][f] = __builtin_amdgcn_mfma_f32_16x16x32_bf16(a[m], bb[f], acc[m][f], 0, 0, 0);
    }
  }
#pragma unroll
  for (int m = 0; m < 2; ++m)
#pragma unroll
    for (int f = 0; f < 4; ++f)
#pragma unroll
      for (int r = 0; r < 4; ++r)
        ob[(size_t)(e0 + 32 * we + 16 * m + 4 * lg + r) * HWN + n0 + 64 * wn + 16 * f + lr] = acc[m][f][r];
}

extern "C" void kernel_launch(void* const* d_in, const int* in_sizes, int n_in,
                              void* d_out, int out_size, void* d_ws, size_t ws_size,
                              hipStream_t stream) {
  const float* x     = (const float*)d_in[0];
  const float* Wqkv  = (const float*)d_in[1];
  const float* Wlin  = (const float*)d_in[2];
  const float* sigma = (const float*)d_in[3];
  float* out = (float*)d_out;

  const size_t perB =
      (size_t)HWN * CCH * 2 +   // xT
      (size_t)384 * HWN * 2 +   // Tqk
      (size_t)HWN * CCH * 2 +   // Vt
      (size_t)256 * 384 * 4 +   // norm2p
      (size_t)384 * 4 +         // invn
      (size_t)SPLIT * CCH * CCH * 4 + // Gpart
      (size_t)CCH * CCH * 4 +   // S
      (size_t)CCH * CCH * 2;    // Mt
  int per = (ws_size >= (size_t)NB * perB) ? NB : 1;

  for (int b0 = 0; b0 < NB; b0 += per) {
    char* base = (char*)d_ws;
    ushort* xT   = (ushort*)base;
    ushort* Tqk  = xT + (size_t)per * HWN * CCH;
    ushort* Vt   = Tqk + (size_t)per * 384 * HWN;
    float* norm2p = (float*)(Vt + (size_t)per * HWN * CCH);
    float* invn  = norm2p + (size_t)per * 256 * 384;
    float* Gpart = invn + (size_t)per * 384;
    float* S     = Gpart + (size_t)per * SPLIT * CCH * CCH;
    ushort* Mt   = (ushort*)(S + (size_t)per * CCH * CCH);
    const float* xb = x + (size_t)b0 * CCH * HWN;
    float* ob = out + (size_t)b0 * CCH * HWN;

    k1_xpose  <<<dim3(256, 3, per), 256, 0, stream>>>(xb, xT);
    k2_qkv    <<<dim3(9, 128, per), 256, 0, stream>>>(xT, Wqkv, Tqk, Vt, norm2p);
    k3_invn   <<<dim3(384, per), 256, 0, stream>>>(norm2p, invn);
    k4_gram   <<<dim3(9, SPLIT, per), 256, 0, stream>>>(Tqk, Gpart);
    k5_softmax<<<dim3(192, per), 64, 0, stream>>>(Gpart, invn, sigma, S);
    k6_mlin   <<<dim3(192, per), 192, 0, stream>>>(S, Wlin, Mt);
    k7_out    <<<dim3(3, 128, per), 256, 0, stream>>>(Mt, Vt, ob);
  }
}

// Round 4
// 143.763 us; speedup vs baseline: 2.9798x; 1.1529x over previous
//
#include <hip/hip_runtime.h>

#define CCH 192
#define HWN 16384
#define NB  4
#define SPLIT 16

typedef __attribute__((ext_vector_type(8))) short bf16x8;
typedef __attribute__((ext_vector_type(4))) float f32x4;

__device__ __forceinline__ ushort f2bf(float f) {
  union { float f; unsigned u; } v; v.f = f;
  return (ushort)((v.u + 0x7fffu + ((v.u >> 16) & 1u)) >> 16);
}

__device__ __forceinline__ float wsum(float v) {
#pragma unroll
  for (int off = 32; off > 0; off >>= 1) v += __shfl_xor(v, off, 64);
  return v;
}
__device__ __forceinline__ float wmax(float v) {
#pragma unroll
  for (int off = 32; off > 0; off >>= 1) v = fmaxf(v, __shfl_xor(v, off, 64));
  return v;
}

// K0: Wqkv f32 [c][576] -> Wb bf16 [j][c] (j-major), 64x64 LDS transpose tiles
__global__ __launch_bounds__(256) void k0_wconv(const float* __restrict__ Wqkv, ushort* __restrict__ Wb) {
  int j0 = blockIdx.x * 64, c0 = blockIdx.y * 64;
  __shared__ float L[64][65];
  int t = threadIdx.x;
#pragma unroll
  for (int p = 0; p < 4; ++p) {
    int idx = t + 256 * p;
    int row = idx >> 4, col = (idx & 15) << 2;   // row = c, col = j
    float4 v = *reinterpret_cast<const float4*>(&Wqkv[(size_t)(c0 + row) * 576 + j0 + col]);
    L[row][col] = v.x; L[row][col + 1] = v.y; L[row][col + 2] = v.z; L[row][col + 3] = v.w;
  }
  __syncthreads();
#pragma unroll
  for (int p = 0; p < 4; ++p) {
    int idx = t + 256 * p;
    int jrow = idx >> 4, c4 = (idx & 15) << 2;
    ushort4 o;
    o.x = f2bf(L[c4 + 0][jrow]);
    o.y = f2bf(L[c4 + 1][jrow]);
    o.z = f2bf(L[c4 + 2][jrow]);
    o.w = f2bf(L[c4 + 3][jrow]);
    *reinterpret_cast<ushort4*>(&Wb[(size_t)(j0 + jrow) * CCH + c0 + c4]) = o;
  }
}

// K1: x[c][n] f32 -> xT[n][c] bf16, 64x64 LDS tiles
__global__ __launch_bounds__(256) void k1_xpose(const float* __restrict__ x, ushort* __restrict__ xT) {
  int z = blockIdx.z;
  const float* xb = x + (size_t)z * CCH * HWN;
  ushort* xTb = xT + (size_t)z * HWN * CCH;
  int n0 = blockIdx.x * 64, c0 = blockIdx.y * 64;
  __shared__ float L[64][65];
  int t = threadIdx.x;
#pragma unroll
  for (int p = 0; p < 4; ++p) {
    int idx = t + 256 * p;
    int row = idx >> 4, col = (idx & 15) << 2;
    float4 v = *reinterpret_cast<const float4*>(&xb[(size_t)(c0 + row) * HWN + n0 + col]);
    L[row][col] = v.x; L[row][col + 1] = v.y; L[row][col + 2] = v.z; L[row][col + 3] = v.w;
  }
  __syncthreads();
#pragma unroll
  for (int p = 0; p < 4; ++p) {
    int idx = t + 256 * p;
    int nl = idx >> 4, c4 = (idx & 15) << 2;
    ushort4 o;
    o.x = f2bf(L[c4 + 0][nl]);
    o.y = f2bf(L[c4 + 1][nl]);
    o.z = f2bf(L[c4 + 2][nl]);
    o.w = f2bf(L[c4 + 3][nl]);
    *reinterpret_cast<ushort4*>(&xTb[(size_t)(n0 + nl) * CCH + c0 + c4]) = o;
  }
}

// K2: qkv GEMM. D[n][j] = sum_c xT[n][c] * Wb[j][c].  W fragments preloaded to registers.
// j-tiles 0..5 -> Tqk[j][n] bf16 (direct packed stores) + norm2 partials; 6..8 -> Vt[n][c] bf16.
__global__ __launch_bounds__(256) void k2_qkv(
    const ushort* __restrict__ xT, const ushort* __restrict__ Wb,
    ushort* __restrict__ Tqk, ushort* __restrict__ Vt, float* __restrict__ norm2p)
{
  int z = blockIdx.z;
  const ushort* xTb = xT + (size_t)z * HWN * CCH;
  ushort* Tb = Tqk + (size_t)z * 384 * HWN;
  ushort* Vb = Vt + (size_t)z * HWN * CCH;
  float* npb = norm2p + (size_t)z * 256 * 384;
  int nt = blockIdx.x, jt = blockIdx.y;
  int n0 = nt * 128, j0 = jt * 64;
  __shared__ __align__(16) ushort As[128 * 104];   // 26624 B -> 6 blocks/CU
  int t = threadIdx.x, l = t & 63, w = t >> 6;
  int wn = w >> 1, wj = w & 1, lg = l >> 4, lr = l & 15;
  // preload all W B-fragments (loop-invariant, L2-resident)
  bf16x8 bfrag[2][3][2];
#pragma unroll
  for (int h = 0; h < 2; ++h)
#pragma unroll
    for (int k3 = 0; k3 < 3; ++k3)
#pragma unroll
      for (int f = 0; f < 2; ++f)
        bfrag[h][k3][f] = *reinterpret_cast<const bf16x8*>(
            &Wb[(size_t)(j0 + 32 * wj + 16 * f + lr) * CCH + 96 * h + 32 * k3 + 8 * lg]);
  f32x4 acc[4][2] = {};
  for (int h = 0; h < 2; ++h) {
    if (h) __syncthreads();
    for (int i = t; i < 128 * 12; i += 256) {
      int row = i / 12, slot = i % 12;
      *reinterpret_cast<int4*>(&As[row * 104 + slot * 8]) =
          *reinterpret_cast<const int4*>(&xTb[(size_t)(n0 + row) * CCH + 96 * h + slot * 8]);
    }
    __syncthreads();
#pragma unroll
    for (int k3 = 0; k3 < 3; ++k3) {
      bf16x8 a[4];
#pragma unroll
      for (int m = 0; m < 4; ++m)
        a[m] = *reinterpret_cast<const bf16x8*>(&As[(64 * wn + 16 * m + lr) * 104 + k3 * 32 + lg * 8]);
#pragma unroll
      for (int m = 0; m < 4; ++m)
#pragma unroll
        for (int f = 0; f < 2; ++f)
          acc[m][f] = __builtin_amdgcn_mfma_f32_16x16x32_bf16(a[m], bfrag[h][k3][f], acc[m][f], 0, 0, 0);
    }
  }
  if (jt >= 6) {
    int cb = (jt - 6) * 64 + 32 * wj;
#pragma unroll
    for (int m = 0; m < 4; ++m)
#pragma unroll
      for (int f = 0; f < 2; ++f)
#pragma unroll
        for (int r = 0; r < 4; ++r)
          Vb[(size_t)(n0 + 64 * wn + 16 * m + 4 * lg + r) * CCH + cb + 16 * f + lr] = f2bf(acc[m][f][r]);
  } else {
    int jb = j0 + 32 * wj;
#pragma unroll
    for (int f = 0; f < 2; ++f) {
      float sq = 0.f;
      int j = jb + 16 * f + lr;
#pragma unroll
      for (int m = 0; m < 4; ++m) {
        int nb = n0 + 64 * wn + 16 * m + 4 * lg;
        unsigned p0 = (unsigned)f2bf(acc[m][f][0]) | ((unsigned)f2bf(acc[m][f][1]) << 16);
        unsigned p1 = (unsigned)f2bf(acc[m][f][2]) | ((unsigned)f2bf(acc[m][f][3]) << 16);
        size_t base = (size_t)j * HWN + nb;
        *reinterpret_cast<unsigned*>(&Tb[base]) = p0;
        *reinterpret_cast<unsigned*>(&Tb[base + 2]) = p1;
#pragma unroll
        for (int r = 0; r < 4; ++r) sq += acc[m][f][r] * acc[m][f][r];
      }
      sq += __shfl_xor(sq, 16, 64);
      sq += __shfl_xor(sq, 32, 64);
      if (lg == 0) npb[(size_t)(2 * nt + wn) * 384 + j] = sq;
    }
  }
}

// K3: invn[j] = 1/max(sqrt(sum_nb norm2p[nb][j]), eps)
__global__ __launch_bounds__(256) void k3_invn(const float* __restrict__ norm2p, float* __restrict__ invn) {
  int z = blockIdx.y, j = blockIdx.x;
  const float* npb = norm2p + (size_t)z * 256 * 384;
  int t = threadIdx.x;
  float s = npb[(size_t)t * 384 + j];
  s = wsum(s);
  __shared__ float red[4];
  if ((t & 63) == 0) red[t >> 6] = s;
  __syncthreads();
  if (t == 0) {
    float tot = red[0] + red[1] + red[2] + red[3];
    invn[(size_t)z * 384 + j] = 1.f / fmaxf(sqrtf(tot), 1e-12f);
  }
}

// K4: Gpart[chunk][c][d] = sum over n-chunk of K[c][n]*Q[d][n], bf16 MFMA
__global__ __launch_bounds__(256) void k4_gram(const ushort* __restrict__ Tqk, float* __restrict__ Gpart) {
  int z = blockIdx.z;
  const ushort* Tb = Tqk + (size_t)z * 384 * HWN;
  float* Gb = Gpart + (size_t)z * SPLIT * CCH * CCH;
  int tile = blockIdx.x, chunk = blockIdx.y;
  int ct = tile / 3, dt = tile % 3;
  __shared__ __align__(16) ushort Ks[64 * 72];
  __shared__ __align__(16) ushort Qs[64 * 72];
  int t = threadIdx.x, l = t & 63, w = t >> 6;
  int wc = w >> 1, wd = w & 1, lg = l >> 4, lr = l & 15;
  f32x4 acc[2][2] = {};
  for (int s = 0; s < 16; ++s) {
    int nb = chunk * 1024 + s * 64;
    for (int i = t; i < 512; i += 256) {
      int row = i >> 3, sl = i & 7;
      *reinterpret_cast<int4*>(&Ks[row * 72 + sl * 8]) =
          *reinterpret_cast<const int4*>(&Tb[(size_t)(192 + ct * 64 + row) * HWN + nb + sl * 8]);
      *reinterpret_cast<int4*>(&Qs[row * 72 + sl * 8]) =
          *reinterpret_cast<const int4*>(&Tb[(size_t)(dt * 64 + row) * HWN + nb + sl * 8]);
    }
    __syncthreads();
#pragma unroll
    for (int hh = 0; hh < 2; ++hh) {
      bf16x8 a[2], bb[2];
#pragma unroll
      for (int m = 0; m < 2; ++m)
        a[m] = *reinterpret_cast<const bf16x8*>(&Ks[(32 * wc + 16 * m + lr) * 72 + hh * 32 + lg * 8]);
#pragma unroll
      for (int f = 0; f < 2; ++f)
        bb[f] = *reinterpret_cast<const bf16x8*>(&Qs[(32 * wd + 16 * f + lr) * 72 + hh * 32 + lg * 8]);
#pragma unroll
      for (int m = 0; m < 2; ++m)
#pragma unroll
        for (int f = 0; f < 2; ++f)
          acc[m][f] = __builtin_amdgcn_mfma_f32_16x16x32_bf16(a[m], bb[f], acc[m][f], 0, 0, 0);
    }
    __syncthreads();
  }
#pragma unroll
  for (int m = 0; m < 2; ++m)
#pragma unroll
    for (int f = 0; f < 2; ++f)
#pragma unroll
      for (int r = 0; r < 4; ++r)
        Gb[(size_t)(chunk * CCH + ct * 64 + 32 * wc + 16 * m + 4 * lg + r) * CCH +
           dt * 64 + 32 * wd + 16 * f + lr] = acc[m][f][r];
}

// K5: reduce Gpart over chunks, scale, softmax over d -> S
__global__ __launch_bounds__(64) void k5_softmax(
    const float* __restrict__ Gpart, const float* __restrict__ invn,
    const float* __restrict__ sigma, float* __restrict__ S)
{
  int c = blockIdx.x, z = blockIdx.y;
  const float* Gb = Gpart + (size_t)z * SPLIT * CCH * CCH;
  const float* inb = invn + (size_t)z * 384;
  float sig = sigma[0];
  float ink = inb[192 + c];
  float lv[3];
#pragma unroll
  for (int r = 0; r < 3; ++r) {
    int d = threadIdx.x + 64 * r;
    float s = 0.f;
    for (int ch = 0; ch < SPLIT; ++ch)
      s += Gb[(size_t)(ch * CCH + c) * CCH + d];
    lv[r] = s * ink * inb[d] * sig;
  }
  float m = fmaxf(lv[0], fmaxf(lv[1], lv[2]));
  m = wmax(m);
  float e[3], tot = 0.f;
#pragma unroll
  for (int r = 0; r < 3; ++r) { e[r] = __expf(lv[r] - m); tot += e[r]; }
  tot = wsum(tot);
  float inv = 1.f / tot;
  float* Sb = S + (size_t)z * CCH * CCH;
#pragma unroll
  for (int r = 0; r < 3; ++r) Sb[(size_t)c * CCH + threadIdx.x + 64 * r] = e[r] * inv;
}

// K6: Mt[e][c] = sum_d S[c][d] * Wlin[d][e]  (bf16 out, transposed for K7 A-side)
__global__ __launch_bounds__(192) void k6_mlin(
    const float* __restrict__ S, const float* __restrict__ Wlin, ushort* __restrict__ Mt)
{
  int z = blockIdx.y, c = blockIdx.x, e = threadIdx.x;
  const float* Sb = S + (size_t)z * CCH * CCH;
  float s = 0.f;
  for (int d = 0; d < CCH; ++d) s += Sb[(size_t)c * CCH + d] * Wlin[(size_t)d * CCH + e];
  Mt[(size_t)z * CCH * CCH + (size_t)e * CCH + c] = f2bf(s);
}

// K7: out[e][n] = sum_c Mt[e][c] * Vt[n][c].  M fragments preloaded to registers.
__global__ __launch_bounds__(256) void k7_out(
    const ushort* __restrict__ Mt, const ushort* __restrict__ Vt, float* __restrict__ out)
{
  int z = blockIdx.z;
  const ushort* Mb = Mt + (size_t)z * CCH * CCH;
  const ushort* Vb = Vt + (size_t)z * HWN * CCH;
  float* ob = out + (size_t)z * CCH * HWN;
  int nt = blockIdx.x, et = blockIdx.y;
  int e0 = et * 64, n0 = nt * 128;
  __shared__ __align__(16) ushort Vs[128 * 104];   // 26624 B -> 6 blocks/CU
  int t = threadIdx.x, l = t & 63, w = t >> 6;
  int wn = w >> 1, we = w & 1, lg = l >> 4, lr = l & 15;
  bf16x8 afrag[2][3][2];
#pragma unroll
  for (int h = 0; h < 2; ++h)
#pragma unroll
    for (int k3 = 0; k3 < 3; ++k3)
#pragma unroll
      for (int m = 0; m < 2; ++m)
        afrag[h][k3][m] = *reinterpret_cast<const bf16x8*>(
            &Mb[(size_t)(e0 + 32 * we + 16 * m + lr) * CCH + 96 * h + 32 * k3 + 8 * lg]);
  f32x4 acc[2][4] = {};
  for (int h = 0; h < 2; ++h) {
    if (h) __syncthreads();
    for (int i = t; i < 128 * 12; i += 256) {
      int row = i / 12, slot = i % 12;
      *reinterpret_cast<int4*>(&Vs[row * 104 + slot * 8]) =
          *reinterpret_cast<const int4*>(&Vb[(size_t)(n0 + row) * CCH + 96 * h + slot * 8]);
    }
    __syncthreads();
#pragma unroll
    for (int k3 = 0; k3 < 3; ++k3) {
      bf16x8 bb[4];
#pragma unroll
      for (int f = 0; f < 4; ++f)
        bb[f] = *reinterpret_cast<const bf16x8*>(&Vs[(64 * wn + 16 * f + lr) * 104 + k3 * 32 + lg * 8]);
#pragma unroll
      for (int m = 0; m < 2; ++m)
#pragma unroll
        for (int f = 0; f < 4; ++f)
          acc[m][f] = __builtin_amdgcn_mfma_f32_16x16x32_bf16(afrag[h][k3][m], bb[f], acc[m][f], 0, 0, 0);
    }
  }
#pragma unroll
  for (int m = 0; m < 2; ++m)
#pragma unroll
    for (int f = 0; f < 4; ++f)
#pragma unroll
      for (int r = 0; r < 4; ++r)
        ob[(size_t)(e0 + 32 * we + 16 * m + 4 * lg + r) * HWN + n0 + 64 * wn + 16 * f + lr] = acc[m][f][r];
}

extern "C" void kernel_launch(void* const* d_in, const int* in_sizes, int n_in,
                              void* d_out, int out_size, void* d_ws, size_t ws_size,
                              hipStream_t stream) {
  const float* x     = (const float*)d_in[0];
  const float* Wqkv  = (const float*)d_in[1];
  const float* Wlin  = (const float*)d_in[2];
  const float* sigma = (const float*)d_in[3];
  float* out = (float*)d_out;

  const size_t wbElems = (size_t)576 * CCH;           // Wb bf16
  const size_t perB =
      (size_t)HWN * CCH * 2 +   // xT
      (size_t)384 * HWN * 2 +   // Tqk
      (size_t)HWN * CCH * 2 +   // Vt
      (size_t)256 * 384 * 4 +   // norm2p
      (size_t)384 * 4 +         // invn
      (size_t)SPLIT * CCH * CCH * 4 + // Gpart
      (size_t)CCH * CCH * 4 +   // S
      (size_t)CCH * CCH * 2;    // Mt
  int per = (ws_size >= wbElems * 2 + (size_t)NB * perB) ? NB : 1;

  ushort* Wb = (ushort*)d_ws;
  k0_wconv<<<dim3(9, 3), 256, 0, stream>>>(Wqkv, Wb);

  for (int b0 = 0; b0 < NB; b0 += per) {
    char* base = (char*)d_ws + wbElems * 2;
    ushort* xT   = (ushort*)base;
    ushort* Tqk  = xT + (size_t)per * HWN * CCH;
    ushort* Vt   = Tqk + (size_t)per * 384 * HWN;
    float* norm2p = (float*)(Vt + (size_t)per * HWN * CCH);
    float* invn  = norm2p + (size_t)per * 256 * 384;
    float* Gpart = invn + (size_t)per * 384;
    float* S     = Gpart + (size_t)per * SPLIT * CCH * CCH;
    ushort* Mt   = (ushort*)(S + (size_t)per * CCH * CCH);
    const float* xb = x + (size_t)b0 * CCH * HWN;
    float* ob = out + (size_t)b0 * CCH * HWN;

    k1_xpose  <<<dim3(256, 3, per), 256, 0, stream>>>(xb, xT);
    k2_qkv    <<<dim3(128, 9, per), 256, 0, stream>>>(xT, Wb, Tqk, Vt, norm2p);
    k3_invn   <<<dim3(384, per), 256, 0, stream>>>(norm2p, invn);
    k4_gram   <<<dim3(9, SPLIT, per), 256, 0, stream>>>(Tqk, Gpart);
    k5_softmax<<<dim3(192, per), 64, 0, stream>>>(Gpart, invn, sigma, S);
    k6_mlin   <<<dim3(192, per), 192, 0, stream>>>(S, Wlin, Mt);
    k7_out    <<<dim3(128, 3, per), 256, 0, stream>>>(Mt, Vt, ob);
  }
}